// Round 1
// baseline (4947.220 us; speedup 1.0000x reference)
//
#include <hip/hip_runtime.h>

#define N_NODES 50000
#define N_EDGES 640000
#define EPS 1e-5f

// ---------------- degree: deg[i] = #edges with dst==i ----------------
__global__ void deg_kernel(const int* __restrict__ dst, float* __restrict__ deg) {
    int e = blockIdx.x * blockDim.x + threadIdx.x;
    if (e < N_EDGES) atomicAdd(&deg[dst[e]], 1.0f);
}

// ---------------- scatter: agg[dst] += h[src], F = 128 ----------------
// block = 256 threads = 8 edges x 32 lanes (each lane: one float4 = 4 feats)
__global__ void scatter_kernel(const float* __restrict__ h, const int* __restrict__ src,
                               const int* __restrict__ dst, float* __restrict__ agg) {
    int lane = threadIdx.x & 31;
    int erow = threadIdx.x >> 5;
    int e = blockIdx.x * 8 + erow;
    if (e >= N_EDGES) return;
    int s = src[e];
    int d = dst[e];
    const float4 v = ((const float4*)(h + (size_t)s * 128))[lane];
    float* a = agg + (size_t)d * 128 + lane * 4;
    atomicAdd(a + 0, v.x);
    atomicAdd(a + 1, v.y);
    atomicAdd(a + 2, v.z);
    atomicAdd(a + 3, v.w);
}

// ---------------- fused SAGE linear: out = h@Ws + (agg/deg)@Wn + b ----------------
// K = 128 fixed. NC = output cols (128 or 64). Block: 256 threads, 32 rows/block.
template<int NC>
__global__ void sage_gemm(const float* __restrict__ h, const float* __restrict__ agg,
                          const float* __restrict__ deg,
                          const float* __restrict__ Ws, const float* __restrict__ Wn,
                          const float* __restrict__ bias, float* __restrict__ out) {
    __shared__ float sh[32][128];
    __shared__ float sa[32][128];
    const int row0 = blockIdx.x * 32;
    const int t = threadIdx.x;

    // stage 32x128 tiles of h and agg (agg pre-divided by deg); 1024 float4s / 256 thr = 4 each
    #pragma unroll
    for (int i = 0; i < 4; ++i) {
        int idx = t + i * 256;          // float4 slot in tile
        int r   = idx >> 5;             // 32 float4 per row
        int c4  = idx & 31;
        int row = row0 + r;
        float4 vh = make_float4(0.f, 0.f, 0.f, 0.f);
        float4 va = vh;
        float sc = 0.f;
        if (row < N_NODES) {
            vh = ((const float4*)(h   + (size_t)row * 128))[c4];
            va = ((const float4*)(agg + (size_t)row * 128))[c4];
            sc = 1.0f / fmaxf(deg[row], 1.0f);
        }
        ((float4*)sh[r])[c4] = vh;
        va.x *= sc; va.y *= sc; va.z *= sc; va.w *= sc;
        ((float4*)sa[r])[c4] = va;
    }
    __syncthreads();

    constexpr int GROUPS = 256 / NC;     // threads stacked per column
    constexpr int RPT    = 32 / GROUPS;  // rows per thread
    const int c  = t % NC;
    const int rg = t / NC;

    float acc[RPT];
    #pragma unroll
    for (int r = 0; r < RPT; ++r) acc[r] = 0.f;

    #pragma unroll 4
    for (int k = 0; k < 128; ++k) {
        float ws = Ws[k * NC + c];
        float wn = Wn[k * NC + c];
        #pragma unroll
        for (int r = 0; r < RPT; ++r) {
            int rr = rg * RPT + r;
            acc[r] = fmaf(sh[rr][k], ws, acc[r]);
            acc[r] = fmaf(sa[rr][k], wn, acc[r]);
        }
    }

    float bb = bias[c];
    #pragma unroll
    for (int r = 0; r < RPT; ++r) {
        int row = row0 + rg * RPT + r;
        if (row < N_NODES) out[(size_t)row * NC + c] = acc[r] + bb;
    }
}

// ---------------- batchnorm stats: per-column sum & sumsq over rows ----------------
// block = 128 threads (1 per column); each block does 256 rows; atomic partial sums.
__global__ void bn_stats(const float* __restrict__ h, float* __restrict__ sums,
                         float* __restrict__ sqs) {
    int c  = threadIdx.x;
    int r0 = blockIdx.x * 256;
    int rend = min(r0 + 256, N_NODES);
    float s = 0.f, q = 0.f;
    for (int r = r0; r < rend; ++r) {
        float v = h[(size_t)r * 128 + c];
        s += v;
        q += v * v;
    }
    atomicAdd(&sums[c], s);
    atomicAdd(&sqs[c], q);
}

// 1 block x 128 threads: scale/shift from stats
__global__ void bn_finalize(const float* __restrict__ sums, const float* __restrict__ sqs,
                            const float* __restrict__ g, const float* __restrict__ beta,
                            float* __restrict__ scale, float* __restrict__ shift) {
    int c = threadIdx.x;
    float mean = sums[c] * (1.0f / N_NODES);
    float var  = sqs[c] * (1.0f / N_NODES) - mean * mean;
    float rstd = rsqrtf(var + EPS);
    float sc = rstd * g[c];
    scale[c] = sc;
    shift[c] = beta[c] - mean * sc;
}

// fused BN apply + ReLU, in place; one float4 per thread
__global__ void bn_relu(float* __restrict__ h, const float* __restrict__ scale,
                        const float* __restrict__ shift) {
    size_t i = (size_t)blockIdx.x * blockDim.x + threadIdx.x;
    if (i >= (size_t)N_NODES * 32) return;
    float4 v = ((const float4*)h)[i];
    int c4 = (int)(i & 31) * 4;
    v.x = fmaxf(fmaf(v.x, scale[c4 + 0], shift[c4 + 0]), 0.f);
    v.y = fmaxf(fmaf(v.y, scale[c4 + 1], shift[c4 + 1]), 0.f);
    v.z = fmaxf(fmaf(v.z, scale[c4 + 2], shift[c4 + 2]), 0.f);
    v.w = fmaxf(fmaf(v.w, scale[c4 + 3], shift[c4 + 3]), 0.f);
    ((float4*)h)[i] = v;
}

extern "C" void kernel_launch(void* const* d_in, const int* in_sizes, int n_in,
                              void* d_out, int out_size, void* d_ws, size_t ws_size,
                              hipStream_t stream) {
    const float* x    = (const float*)d_in[0];
    const int*   src  = (const int*)d_in[1];
    const int*   dst  = (const int*)d_in[2];
    const float* Ws0  = (const float*)d_in[3];
    const float* Wn0  = (const float*)d_in[4];
    const float* b0   = (const float*)d_in[5];
    const float* Ws1  = (const float*)d_in[6];
    const float* Wn1  = (const float*)d_in[7];
    const float* b1   = (const float*)d_in[8];
    const float* Ws2  = (const float*)d_in[9];
    const float* Wn2  = (const float*)d_in[10];
    const float* b2   = (const float*)d_in[11];
    const float* g0   = (const float*)d_in[12];
    const float* bt0  = (const float*)d_in[13];
    const float* g1   = (const float*)d_in[14];
    const float* bt1  = (const float*)d_in[15];

    char* ws = (char*)d_ws;
    const size_t HBYTES = (size_t)N_NODES * 128 * sizeof(float); // 25.6 MB
    float* deg  = (float*)(ws);                       // 200 KB
    float* agg  = (float*)(ws + 204800);
    float* h1   = (float*)(ws + 204800 + HBYTES);
    float* h2   = (float*)(ws + 204800 + 2 * HBYTES);
    float* sums = (float*)(ws + 204800 + 3 * HBYTES);
    float* sqs  = sums + 128;
    float* scl  = sums + 256;
    float* shf  = sums + 384;

    float* out = (float*)d_out;

    const int scatter_grid = (N_EDGES + 7) / 8;
    const int gemm_grid    = (N_NODES + 31) / 32;
    const int stats_grid   = (N_NODES + 255) / 256;
    const int relu_grid    = (N_NODES * 32 + 255) / 256;

    // degree (once)
    hipMemsetAsync(deg, 0, (size_t)N_NODES * sizeof(float), stream);
    deg_kernel<<<(N_EDGES + 255) / 256, 256, 0, stream>>>(dst, deg);

    // ---- layer 0 ----
    hipMemsetAsync(agg, 0, HBYTES, stream);
    scatter_kernel<<<scatter_grid, 256, 0, stream>>>(x, src, dst, agg);
    sage_gemm<128><<<gemm_grid, 256, 0, stream>>>(x, agg, deg, Ws0, Wn0, b0, h1);
    hipMemsetAsync(sums, 0, 256 * sizeof(float), stream);
    bn_stats<<<stats_grid, 128, 0, stream>>>(h1, sums, sqs);
    bn_finalize<<<1, 128, 0, stream>>>(sums, sqs, g0, bt0, scl, shf);
    bn_relu<<<relu_grid, 256, 0, stream>>>(h1, scl, shf);

    // ---- layer 1 ----
    hipMemsetAsync(agg, 0, HBYTES, stream);
    scatter_kernel<<<scatter_grid, 256, 0, stream>>>(h1, src, dst, agg);
    sage_gemm<128><<<gemm_grid, 256, 0, stream>>>(h1, agg, deg, Ws1, Wn1, b1, h2);
    hipMemsetAsync(sums, 0, 256 * sizeof(float), stream);
    bn_stats<<<stats_grid, 128, 0, stream>>>(h2, sums, sqs);
    bn_finalize<<<1, 128, 0, stream>>>(sums, sqs, g1, bt1, scl, shf);
    bn_relu<<<relu_grid, 256, 0, stream>>>(h2, scl, shf);

    // ---- layer 2 ----
    hipMemsetAsync(agg, 0, HBYTES, stream);
    scatter_kernel<<<scatter_grid, 256, 0, stream>>>(h2, src, dst, agg);
    sage_gemm<64><<<gemm_grid, 256, 0, stream>>>(h2, agg, deg, Ws2, Wn2, b2, out);
}

// Round 2
// 525.302 us; speedup vs baseline: 9.4179x; 9.4179x over previous
//
#include <hip/hip_runtime.h>

#define N_NODES 50000
#define N_EDGES 640000
#define EPS 1e-5f
#define NBLK_SCAN 196   // ceil(50000/256)

// ---------------- CSR build ----------------
__global__ void hist_kernel(const int* __restrict__ dst, int* __restrict__ counts) {
    int e = blockIdx.x * 256 + threadIdx.x;
    if (e < N_EDGES) atomicAdd(&counts[dst[e]], 1);
}

__global__ void scan1_kernel(const int* __restrict__ counts, int* __restrict__ incl,
                             int* __restrict__ bsums) {
    __shared__ int tmp[256];
    int t = threadIdx.x;
    int i = blockIdx.x * 256 + t;
    tmp[t] = (i < N_NODES) ? counts[i] : 0;
    __syncthreads();
    for (int off = 1; off < 256; off <<= 1) {
        int add = (t >= off) ? tmp[t - off] : 0;
        __syncthreads();
        tmp[t] += add;
        __syncthreads();
    }
    if (i < N_NODES) incl[i] = tmp[t];
    if (t == 255) bsums[blockIdx.x] = tmp[255];
}

__global__ void scan2_kernel(const int* __restrict__ bsums, int* __restrict__ boff) {
    __shared__ int tmp[256];
    int t = threadIdx.x;
    tmp[t] = (t < NBLK_SCAN) ? bsums[t] : 0;
    __syncthreads();
    for (int off = 1; off < 256; off <<= 1) {
        int add = (t >= off) ? tmp[t - off] : 0;
        __syncthreads();
        tmp[t] += add;
        __syncthreads();
    }
    if (t < NBLK_SCAN) boff[t] = (t == 0) ? 0 : tmp[t - 1];
}

__global__ void scan3_kernel(const int* __restrict__ counts, const int* __restrict__ incl,
                             const int* __restrict__ boff, int* __restrict__ rowptr,
                             int* __restrict__ cursor, float* __restrict__ rdeg) {
    int i = blockIdx.x * 256 + threadIdx.x;
    if (i >= N_NODES) return;
    int c = counts[i];
    int inc = incl[i] + boff[blockIdx.x];
    int start = inc - c;
    rowptr[i] = start;
    cursor[i] = start;
    rdeg[i] = 1.0f / fmaxf((float)c, 1.0f);
    if (i == N_NODES - 1) rowptr[N_NODES] = inc;
}

__global__ void fill_kernel(const int* __restrict__ src, const int* __restrict__ dst,
                            int* __restrict__ cursor, int* __restrict__ esrc) {
    int e = blockIdx.x * 256 + threadIdx.x;
    if (e < N_EDGES) {
        int p = atomicAdd(&cursor[dst[e]], 1);
        esrc[p] = src[e];
    }
}

// ---------------- gather mean: one 64-lane wave per node, float2/lane ----------------
__global__ void gather_kernel(const float* __restrict__ h, const int* __restrict__ rowptr,
                              const int* __restrict__ esrc, const float* __restrict__ rdeg,
                              float* __restrict__ agg) {
    int node = blockIdx.x * 4 + (threadIdx.x >> 6);
    int lane = threadIdx.x & 63;
    if (node >= N_NODES) return;
    int beg = rowptr[node], end = rowptr[node + 1];
    float accx = 0.f, accy = 0.f;
    int j = beg;
    for (; j + 1 < end; j += 2) {
        int s0 = esrc[j], s1 = esrc[j + 1];
        float2 v0 = ((const float2*)(h + (size_t)s0 * 128))[lane];
        float2 v1 = ((const float2*)(h + (size_t)s1 * 128))[lane];
        accx += v0.x + v1.x;
        accy += v0.y + v1.y;
    }
    if (j < end) {
        int s = esrc[j];
        float2 v = ((const float2*)(h + (size_t)s * 128))[lane];
        accx += v.x;
        accy += v.y;
    }
    float r = rdeg[node];
    ((float2*)(agg + (size_t)node * 128))[lane] = make_float2(accx * r, accy * r);
}

// ---------------- fused SAGE linear: out = h@Ws + agg@Wn + b ----------------
// Tile: 64 rows x NC cols. Each thread: 4x4 outputs. K chunked by 32, staged in LDS.
// h/agg staged TRANSPOSED so inner loop is 4x ds_read_b128 + 32 fma per k.
template<int NC>
__global__ void sage_gemm(const float* __restrict__ h, const float* __restrict__ agg,
                          const float* __restrict__ Ws, const float* __restrict__ Wn,
                          const float* __restrict__ bias, float* __restrict__ out) {
    constexpr int THREADS = NC * 4;   // (NC/4) col-groups x 16 row-groups
    __shared__ float sh_t[32][68];    // [k][row], pad 68 keeps float4 alignment
    __shared__ float sa_t[32][68];
    __shared__ float sw[32][NC];
    __shared__ float sn[32][NC];

    const int t = threadIdx.x;
    const int tx = t % (NC / 4);
    const int ty = t / (NC / 4);      // 0..15
    const int row0 = blockIdx.x * 64;

    float acc[4][4];
    #pragma unroll
    for (int i = 0; i < 4; ++i)
        #pragma unroll
        for (int j = 0; j < 4; ++j) acc[i][j] = 0.f;

    for (int kk = 0; kk < 4; ++kk) {
        // stage h/agg transposed: 512 float4 per tensor
        #pragma unroll
        for (int it = 0; it < 512 / THREADS; ++it) {
            int idx = t + it * THREADS;
            int r = idx >> 3, c4 = idx & 7;
            int row = row0 + r;
            float4 hv = make_float4(0.f, 0.f, 0.f, 0.f);
            float4 av = hv;
            if (row < N_NODES) {
                hv = *(const float4*)(h + (size_t)row * 128 + kk * 32 + c4 * 4);
                av = *(const float4*)(agg + (size_t)row * 128 + kk * 32 + c4 * 4);
            }
            int k0 = c4 * 4;
            sh_t[k0 + 0][r] = hv.x; sh_t[k0 + 1][r] = hv.y;
            sh_t[k0 + 2][r] = hv.z; sh_t[k0 + 3][r] = hv.w;
            sa_t[k0 + 0][r] = av.x; sa_t[k0 + 1][r] = av.y;
            sa_t[k0 + 2][r] = av.z; sa_t[k0 + 3][r] = av.w;
        }
        // stage weights: 8*NC float4 per matrix
        #pragma unroll
        for (int it = 0; it < (8 * NC) / THREADS; ++it) {
            int idx = t + it * THREADS;
            int kr = idx / (NC / 4), c4 = idx % (NC / 4);
            ((float4*)sw[kr])[c4] = ((const float4*)(Ws + (size_t)(kk * 32 + kr) * NC))[c4];
            ((float4*)sn[kr])[c4] = ((const float4*)(Wn + (size_t)(kk * 32 + kr) * NC))[c4];
        }
        __syncthreads();

        #pragma unroll 8
        for (int k = 0; k < 32; ++k) {
            float4 w_s = *(const float4*)&sw[k][tx * 4];
            float4 w_n = *(const float4*)&sn[k][tx * 4];
            float4 hv = *(const float4*)&sh_t[k][ty * 4];
            float4 av = *(const float4*)&sa_t[k][ty * 4];
            float hx[4] = {hv.x, hv.y, hv.z, hv.w};
            float ax[4] = {av.x, av.y, av.z, av.w};
            float wsj[4] = {w_s.x, w_s.y, w_s.z, w_s.w};
            float wnj[4] = {w_n.x, w_n.y, w_n.z, w_n.w};
            #pragma unroll
            for (int i = 0; i < 4; ++i)
                #pragma unroll
                for (int j = 0; j < 4; ++j)
                    acc[i][j] = fmaf(hx[i], wsj[j], fmaf(ax[i], wnj[j], acc[i][j]));
        }
        __syncthreads();
    }

    float4 b4 = *(const float4*)&bias[tx * 4];
    float bb[4] = {b4.x, b4.y, b4.z, b4.w};
    #pragma unroll
    for (int i = 0; i < 4; ++i) {
        int row = row0 + ty * 4 + i;
        if (row < N_NODES) {
            float4 o;
            o.x = acc[i][0] + bb[0];
            o.y = acc[i][1] + bb[1];
            o.z = acc[i][2] + bb[2];
            o.w = acc[i][3] + bb[3];
            *(float4*)(out + (size_t)row * NC + tx * 4) = o;
        }
    }
}

// ---------------- batchnorm ----------------
__global__ void bn_stats(const float* __restrict__ h, float* __restrict__ sums,
                         float* __restrict__ sqs) {
    int c = threadIdx.x;
    int r0 = blockIdx.x * 256;
    int rend = min(r0 + 256, N_NODES);
    float s = 0.f, q = 0.f;
    for (int r = r0; r < rend; ++r) {
        float v = h[(size_t)r * 128 + c];
        s += v;
        q += v * v;
    }
    atomicAdd(&sums[c], s);
    atomicAdd(&sqs[c], q);
}

__global__ void bn_finalize(const float* __restrict__ sums, const float* __restrict__ sqs,
                            const float* __restrict__ g, const float* __restrict__ beta,
                            float* __restrict__ scale, float* __restrict__ shift) {
    int c = threadIdx.x;
    float mean = sums[c] * (1.0f / N_NODES);
    float var = sqs[c] * (1.0f / N_NODES) - mean * mean;
    float rstd = rsqrtf(var + EPS);
    float sc = rstd * g[c];
    scale[c] = sc;
    shift[c] = beta[c] - mean * sc;
}

__global__ void bn_relu(float* __restrict__ h, const float* __restrict__ scale,
                        const float* __restrict__ shift) {
    size_t i = (size_t)blockIdx.x * blockDim.x + threadIdx.x;
    if (i >= (size_t)N_NODES * 32) return;
    float4 v = ((const float4*)h)[i];
    int c4 = (int)(i & 31) * 4;
    v.x = fmaxf(fmaf(v.x, scale[c4 + 0], shift[c4 + 0]), 0.f);
    v.y = fmaxf(fmaf(v.y, scale[c4 + 1], shift[c4 + 1]), 0.f);
    v.z = fmaxf(fmaf(v.z, scale[c4 + 2], shift[c4 + 2]), 0.f);
    v.w = fmaxf(fmaf(v.w, scale[c4 + 3], shift[c4 + 3]), 0.f);
    ((float4*)h)[i] = v;
}

extern "C" void kernel_launch(void* const* d_in, const int* in_sizes, int n_in,
                              void* d_out, int out_size, void* d_ws, size_t ws_size,
                              hipStream_t stream) {
    const float* x   = (const float*)d_in[0];
    const int*   src = (const int*)d_in[1];
    const int*   dst = (const int*)d_in[2];
    const float* Ws0 = (const float*)d_in[3];
    const float* Wn0 = (const float*)d_in[4];
    const float* b0  = (const float*)d_in[5];
    const float* Ws1 = (const float*)d_in[6];
    const float* Wn1 = (const float*)d_in[7];
    const float* b1  = (const float*)d_in[8];
    const float* Ws2 = (const float*)d_in[9];
    const float* Wn2 = (const float*)d_in[10];
    const float* b2  = (const float*)d_in[11];
    const float* g0  = (const float*)d_in[12];
    const float* bt0 = (const float*)d_in[13];
    const float* g1  = (const float*)d_in[14];
    const float* bt1 = (const float*)d_in[15];

    char* ws = (char*)d_ws;
    const size_t HB = (size_t)N_NODES * 128 * sizeof(float);   // 25.6 MB
    size_t off = 0;
    float* agg    = (float*)(ws + off); off += HB;
    float* h1     = (float*)(ws + off); off += HB;
    float* h2     = (float*)(ws + off); off += HB;
    int*   esrc   = (int*)(ws + off);   off += (size_t)N_EDGES * 4;
    int*   counts = (int*)(ws + off);   off += 200192;
    int*   incl   = (int*)(ws + off);   off += 200192;
    int*   rowptr = (int*)(ws + off);   off += 200192;
    int*   cursor = (int*)(ws + off);   off += 200192;
    float* rdeg   = (float*)(ws + off); off += 200192;
    int*   bsums  = (int*)(ws + off);   off += 1024;
    int*   boff   = (int*)(ws + off);   off += 1024;
    float* sums   = (float*)(ws + off); off += 512;
    float* sqs    = (float*)(ws + off); off += 512;
    float* scl    = (float*)(ws + off); off += 512;
    float* shf    = (float*)(ws + off); off += 512;

    float* out = (float*)d_out;

    const int egrid = (N_EDGES + 255) / 256;    // 2500
    const int ggrid = (N_NODES + 3) / 4;        // 12500
    const int mgrid = (N_NODES + 63) / 64;      // 782
    const int sgrid = (N_NODES + 255) / 256;    // 196
    const int rgrid = (N_NODES * 32 + 255) / 256;

    // ---- CSR build (once) ----
    hipMemsetAsync(counts, 0, (size_t)N_NODES * 4, stream);
    hist_kernel<<<egrid, 256, 0, stream>>>(dst, counts);
    scan1_kernel<<<NBLK_SCAN, 256, 0, stream>>>(counts, incl, bsums);
    scan2_kernel<<<1, 256, 0, stream>>>(bsums, boff);
    scan3_kernel<<<NBLK_SCAN, 256, 0, stream>>>(counts, incl, boff, rowptr, cursor, rdeg);
    fill_kernel<<<egrid, 256, 0, stream>>>(src, dst, cursor, esrc);

    // ---- layer 0 ----
    gather_kernel<<<ggrid, 256, 0, stream>>>(x, rowptr, esrc, rdeg, agg);
    sage_gemm<128><<<mgrid, 512, 0, stream>>>(x, agg, Ws0, Wn0, b0, h1);
    hipMemsetAsync(sums, 0, 1024, stream);
    bn_stats<<<sgrid, 128, 0, stream>>>(h1, sums, sqs);
    bn_finalize<<<1, 128, 0, stream>>>(sums, sqs, g0, bt0, scl, shf);
    bn_relu<<<rgrid, 256, 0, stream>>>(h1, scl, shf);

    // ---- layer 1 ----
    gather_kernel<<<ggrid, 256, 0, stream>>>(h1, rowptr, esrc, rdeg, agg);
    sage_gemm<128><<<mgrid, 512, 0, stream>>>(h1, agg, Ws1, Wn1, b1, h2);
    hipMemsetAsync(sums, 0, 1024, stream);
    bn_stats<<<sgrid, 128, 0, stream>>>(h2, sums, sqs);
    bn_finalize<<<1, 128, 0, stream>>>(sums, sqs, g1, bt1, scl, shf);
    bn_relu<<<rgrid, 256, 0, stream>>>(h2, scl, shf);

    // ---- layer 2 ----
    gather_kernel<<<ggrid, 256, 0, stream>>>(h2, rowptr, esrc, rdeg, agg);
    sage_gemm<64><<<mgrid, 256, 0, stream>>>(h2, agg, Ws2, Wn2, b2, out);
}

// Round 3
// 326.514 us; speedup vs baseline: 15.1516x; 1.6088x over previous
//
#include <hip/hip_runtime.h>

#define N_NODES 50000
#define N_EDGES 640000
#define EPS 1e-5f
#define NBLK_SCAN 196   // ceil(50000/256)

typedef __attribute__((ext_vector_type(8))) short short8;
typedef __attribute__((ext_vector_type(4))) float f32x4;

__device__ inline unsigned short f2bf(float f) {
    unsigned u = __float_as_uint(f);
    u += 0x7fffu + ((u >> 16) & 1u);   // RNE
    return (unsigned short)(u >> 16);
}
__device__ inline float bf2f(unsigned short b) {
    return __uint_as_float(((unsigned)b) << 16);
}
__device__ inline void storev(short* p, float v) { *(unsigned short*)p = f2bf(v); }
__device__ inline void storev(float* p, float v) { *p = v; }

// ---------------- CSR build ----------------
__global__ void hist_kernel(const int* __restrict__ dst, int* __restrict__ counts) {
    int e = blockIdx.x * 256 + threadIdx.x;
    if (e < N_EDGES) atomicAdd(&counts[dst[e]], 1);
}

__global__ void scan1_kernel(const int* __restrict__ counts, int* __restrict__ incl,
                             int* __restrict__ bsums) {
    __shared__ int tmp[256];
    int t = threadIdx.x;
    int i = blockIdx.x * 256 + t;
    tmp[t] = (i < N_NODES) ? counts[i] : 0;
    __syncthreads();
    for (int off = 1; off < 256; off <<= 1) {
        int add = (t >= off) ? tmp[t - off] : 0;
        __syncthreads();
        tmp[t] += add;
        __syncthreads();
    }
    if (i < N_NODES) incl[i] = tmp[t];
    if (t == 255) bsums[blockIdx.x] = tmp[255];
}

__global__ void scan2_kernel(const int* __restrict__ bsums, int* __restrict__ boff) {
    __shared__ int tmp[256];
    int t = threadIdx.x;
    tmp[t] = (t < NBLK_SCAN) ? bsums[t] : 0;
    __syncthreads();
    for (int off = 1; off < 256; off <<= 1) {
        int add = (t >= off) ? tmp[t - off] : 0;
        __syncthreads();
        tmp[t] += add;
        __syncthreads();
    }
    if (t < NBLK_SCAN) boff[t] = (t == 0) ? 0 : tmp[t - 1];
}

__global__ void scan3_kernel(const int* __restrict__ counts, const int* __restrict__ incl,
                             const int* __restrict__ boff, int* __restrict__ rowptr,
                             int* __restrict__ cursor, float* __restrict__ rdeg) {
    int i = blockIdx.x * 256 + threadIdx.x;
    if (i >= N_NODES) return;
    int c = counts[i];
    int inc = incl[i] + boff[blockIdx.x];
    int start = inc - c;
    rowptr[i] = start;
    cursor[i] = start;
    rdeg[i] = 1.0f / fmaxf((float)c, 1.0f);
    if (i == N_NODES - 1) rowptr[N_NODES] = inc;
}

__global__ void fill_kernel(const int* __restrict__ src, const int* __restrict__ dst,
                            int* __restrict__ cursor, int* __restrict__ esrc) {
    int e = blockIdx.x * 256 + threadIdx.x;
    if (e < N_EDGES) {
        int p = atomicAdd(&cursor[dst[e]], 1);
        esrc[p] = src[e];
    }
}

// ---------------- x (f32) -> bf16 ----------------
__global__ void xcvt_kernel(const float* __restrict__ in, short* __restrict__ outp) {
    int i = blockIdx.x * 256 + threadIdx.x;       // 8-elem chunk
    if (i >= N_NODES * 16) return;
    const float4* p = (const float4*)in + 2 * (size_t)i;
    float4 a = p[0], b = p[1];
    short8 v;
    v[0] = (short)f2bf(a.x); v[1] = (short)f2bf(a.y);
    v[2] = (short)f2bf(a.z); v[3] = (short)f2bf(a.w);
    v[4] = (short)f2bf(b.x); v[5] = (short)f2bf(b.y);
    v[6] = (short)f2bf(b.z); v[7] = (short)f2bf(b.w);
    *((short8*)outp + i) = v;
}

// ---------------- pack weights (f32 K x NC) into MFMA B-fragment order, bf16 ----
// Wpk[((ks*(NC/16)+cb)*64 + lane)*8 + j] = W[ks*32 + (lane>>4)*8 + j][cb*16 + (lane&15)]
__global__ void pack_w(const float* __restrict__ W, short* __restrict__ Wpk, int NC) {
    int idx = blockIdx.x * 256 + threadIdx.x;
    int total = 4 * (NC / 16) * 64;
    if (idx >= total) return;
    int lane = idx & 63;
    int cbks = idx >> 6;
    int cb = cbks % (NC / 16);
    int ks = cbks / (NC / 16);
    int col = cb * 16 + (lane & 15);
    int k0 = ks * 32 + ((lane >> 4) << 3);
    short8 v;
    #pragma unroll
    for (int j = 0; j < 8; ++j) v[j] = (short)f2bf(W[(size_t)(k0 + j) * NC + col]);
    *((short8*)Wpk + idx) = v;
}

// ---------------- gather mean (bf16): one 64-lane wave per node ----------------
__global__ void gather_bf16(const short* __restrict__ h, const int* __restrict__ rowptr,
                            const int* __restrict__ esrc, const float* __restrict__ rdeg,
                            short* __restrict__ agg) {
    int node = blockIdx.x * 4 + (threadIdx.x >> 6);
    int lane = threadIdx.x & 63;
    if (node >= N_NODES) return;
    int beg = rowptr[node], end = rowptr[node + 1];
    float ax = 0.f, ay = 0.f;
    int j = beg;
    for (; j + 1 < end; j += 2) {
        int s0 = esrc[j], s1 = esrc[j + 1];
        unsigned v0 = *(const unsigned*)(h + (size_t)s0 * 128 + lane * 2);
        unsigned v1 = *(const unsigned*)(h + (size_t)s1 * 128 + lane * 2);
        ax += __uint_as_float(v0 << 16) + __uint_as_float(v1 << 16);
        ay += __uint_as_float(v0 & 0xffff0000u) + __uint_as_float(v1 & 0xffff0000u);
    }
    if (j < end) {
        unsigned v = *(const unsigned*)(h + (size_t)esrc[j] * 128 + lane * 2);
        ax += __uint_as_float(v << 16);
        ay += __uint_as_float(v & 0xffff0000u);
    }
    float r = rdeg[node];
    unsigned o = ((unsigned)f2bf(ay * r) << 16) | (unsigned)f2bf(ax * r);
    *(unsigned*)(agg + (size_t)node * 128 + lane * 2) = o;
}

// ---------------- MFMA SAGE linear: out = h@Ws + agg@Wn + b ----------------
// Block = 256 thr = 4 waves; each wave a 16-row strip; K=128 per tensor, k-step 32.
template<int NC, typename OUT>
__global__ void sage_mfma(const short* __restrict__ h, const short* __restrict__ agg,
                          const short* __restrict__ Wspk, const short* __restrict__ Wnpk,
                          const float* __restrict__ bias, OUT* __restrict__ out) {
    constexpr int CB = NC / 16;
    const int lane = threadIdx.x & 63;
    const int w = threadIdx.x >> 6;
    const int row_base = blockIdx.x * 64 + w * 16;
    const int arow = row_base + (lane & 15);
    const int koff = (lane >> 4) << 3;     // 0,8,16,24

    short8 zero8 = {0, 0, 0, 0, 0, 0, 0, 0};
    short8 ha[4], aa[4];
    if (arow < N_NODES) {
        const short8* hb = (const short8*)(h + (size_t)arow * 128 + koff);
        const short8* ab = (const short8*)(agg + (size_t)arow * 128 + koff);
        #pragma unroll
        for (int ks = 0; ks < 4; ++ks) {
            ha[ks] = hb[ks * 4];   // ks*32 shorts
            aa[ks] = ab[ks * 4];
        }
    } else {
        #pragma unroll
        for (int ks = 0; ks < 4; ++ks) { ha[ks] = zero8; aa[ks] = zero8; }
    }

    f32x4 zacc = {0.f, 0.f, 0.f, 0.f};
    f32x4 acc[CB];
    #pragma unroll
    for (int c = 0; c < CB; ++c) acc[c] = zacc;

    #pragma unroll
    for (int c = 0; c < CB; ++c) {
        #pragma unroll
        for (int ks = 0; ks < 4; ++ks) {
            short8 b = *((const short8*)Wspk + (ks * CB + c) * 64 + lane);
            acc[c] = __builtin_amdgcn_mfma_f32_16x16x32_bf16(ha[ks], b, acc[c], 0, 0, 0);
        }
        #pragma unroll
        for (int ks = 0; ks < 4; ++ks) {
            short8 b = *((const short8*)Wnpk + (ks * CB + c) * 64 + lane);
            acc[c] = __builtin_amdgcn_mfma_f32_16x16x32_bf16(aa[ks], b, acc[c], 0, 0, 0);
        }
    }

    const int col = lane & 15;
    const int rbase = row_base + ((lane >> 4) << 2);
    #pragma unroll
    for (int c = 0; c < CB; ++c) {
        float bb = bias[c * 16 + col];
        #pragma unroll
        for (int r = 0; r < 4; ++r) {
            int row = rbase + r;
            if (row < N_NODES)
                storev(out + (size_t)row * NC + c * 16 + col, acc[c][r] + bb);
        }
    }
}

// ---------------- batchnorm stats (bf16 input) ----------------
__global__ void bn_stats_bf16(const short* __restrict__ h, float* __restrict__ sums,
                              float* __restrict__ sqs) {
    __shared__ float ls[128], lq[128];
    int t = threadIdx.x;
    if (t < 128) { ls[t] = 0.f; lq[t] = 0.f; }
    __syncthreads();
    int cg = t & 15;    // 8-col group
    int rg = t >> 4;    // 16 rows per sweep
    float s[8] = {0, 0, 0, 0, 0, 0, 0, 0}, q[8] = {0, 0, 0, 0, 0, 0, 0, 0};
    for (int row = blockIdx.x * 16 + rg; row < N_NODES; row += 256 * 16) {
        short8 v = *(const short8*)(h + (size_t)row * 128 + cg * 8);
        #pragma unroll
        for (int j = 0; j < 8; ++j) {
            float f = bf2f((unsigned short)v[j]);
            s[j] += f;
            q[j] += f * f;
        }
    }
    #pragma unroll
    for (int j = 0; j < 8; ++j) {
        atomicAdd(&ls[cg * 8 + j], s[j]);
        atomicAdd(&lq[cg * 8 + j], q[j]);
    }
    __syncthreads();
    if (t < 128) {
        atomicAdd(&sums[t], ls[t]);
        atomicAdd(&sqs[t], lq[t]);
    }
}

__global__ void bn_finalize(const float* __restrict__ sums, const float* __restrict__ sqs,
                            const float* __restrict__ g, const float* __restrict__ beta,
                            float* __restrict__ scale, float* __restrict__ shift) {
    int c = threadIdx.x;
    float mean = sums[c] * (1.0f / N_NODES);
    float var = sqs[c] * (1.0f / N_NODES) - mean * mean;
    float rstd = rsqrtf(var + EPS);
    float sc = rstd * g[c];
    scale[c] = sc;
    shift[c] = beta[c] - mean * sc;
}

// ---------------- BN apply + ReLU (bf16 in place) ----------------
__global__ void bn_relu_bf16(short* __restrict__ h, const float* __restrict__ scale,
                             const float* __restrict__ shift) {
    int i = blockIdx.x * 256 + threadIdx.x;     // 8-elem chunk
    if (i >= N_NODES * 16) return;
    int c0 = (i & 15) * 8;
    short8 v = *((short8*)h + i);
    #pragma unroll
    for (int j = 0; j < 8; ++j) {
        float f = bf2f((unsigned short)v[j]);
        f = fmaxf(fmaf(f, scale[c0 + j], shift[c0 + j]), 0.f);
        v[j] = (short)f2bf(f);
    }
    *((short8*)h + i) = v;
}

extern "C" void kernel_launch(void* const* d_in, const int* in_sizes, int n_in,
                              void* d_out, int out_size, void* d_ws, size_t ws_size,
                              hipStream_t stream) {
    const float* x   = (const float*)d_in[0];
    const int*   src = (const int*)d_in[1];
    const int*   dst = (const int*)d_in[2];
    const float* Ws0 = (const float*)d_in[3];
    const float* Wn0 = (const float*)d_in[4];
    const float* b0  = (const float*)d_in[5];
    const float* Ws1 = (const float*)d_in[6];
    const float* Wn1 = (const float*)d_in[7];
    const float* b1  = (const float*)d_in[8];
    const float* Ws2 = (const float*)d_in[9];
    const float* Wn2 = (const float*)d_in[10];
    const float* b2  = (const float*)d_in[11];
    const float* g0  = (const float*)d_in[12];
    const float* bt0 = (const float*)d_in[13];
    const float* g1  = (const float*)d_in[14];
    const float* bt1 = (const float*)d_in[15];

    char* ws = (char*)d_ws;
    const size_t HB2 = (size_t)N_NODES * 128 * 2;   // bf16 tensor: 12.8 MB
    size_t off = 0;
    short* xb     = (short*)(ws + off); off += HB2;
    short* aggb   = (short*)(ws + off); off += HB2;
    short* h1b    = (short*)(ws + off); off += HB2;
    short* h2b    = (short*)(ws + off); off += HB2;
    int*   esrc   = (int*)(ws + off);   off += (size_t)N_EDGES * 4;
    int*   counts = (int*)(ws + off);   off += 200192;
    int*   incl   = (int*)(ws + off);   off += 200192;
    int*   rowptr = (int*)(ws + off);   off += 200704;
    int*   cursor = (int*)(ws + off);   off += 200192;
    float* rdeg   = (float*)(ws + off); off += 200192;
    int*   bsums  = (int*)(ws + off);   off += 1024;
    int*   boff   = (int*)(ws + off);   off += 1024;
    float* sums   = (float*)(ws + off); off += 512;
    float* sqs    = (float*)(ws + off); off += 512;
    float* scl    = (float*)(ws + off); off += 512;
    float* shf    = (float*)(ws + off); off += 512;
    short* pWs0   = (short*)(ws + off); off += 32768;
    short* pWn0   = (short*)(ws + off); off += 32768;
    short* pWs1   = (short*)(ws + off); off += 32768;
    short* pWn1   = (short*)(ws + off); off += 32768;
    short* pWs2   = (short*)(ws + off); off += 16384;
    short* pWn2   = (short*)(ws + off); off += 16384;

    float* out = (float*)d_out;

    const int egrid = (N_EDGES + 255) / 256;       // 2500
    const int ggrid = (N_NODES + 3) / 4;           // 12500
    const int mgrid = (N_NODES + 63) / 64;         // 782
    const int cgrid = (N_NODES * 16 + 255) / 256;  // 3125

    // ---- prep: x->bf16, weight packing, CSR ----
    xcvt_kernel<<<cgrid, 256, 0, stream>>>(x, xb);
    pack_w<<<8, 256, 0, stream>>>(Ws0, pWs0, 128);
    pack_w<<<8, 256, 0, stream>>>(Wn0, pWn0, 128);
    pack_w<<<8, 256, 0, stream>>>(Ws1, pWs1, 128);
    pack_w<<<8, 256, 0, stream>>>(Wn1, pWn1, 128);
    pack_w<<<4, 256, 0, stream>>>(Ws2, pWs2, 64);
    pack_w<<<4, 256, 0, stream>>>(Wn2, pWn2, 64);
    hipMemsetAsync(counts, 0, (size_t)N_NODES * 4, stream);
    hist_kernel<<<egrid, 256, 0, stream>>>(dst, counts);
    scan1_kernel<<<NBLK_SCAN, 256, 0, stream>>>(counts, incl, bsums);
    scan2_kernel<<<1, 256, 0, stream>>>(bsums, boff);
    scan3_kernel<<<NBLK_SCAN, 256, 0, stream>>>(counts, incl, boff, rowptr, cursor, rdeg);
    fill_kernel<<<egrid, 256, 0, stream>>>(src, dst, cursor, esrc);

    // ---- layer 0 ----
    gather_bf16<<<ggrid, 256, 0, stream>>>(xb, rowptr, esrc, rdeg, aggb);
    sage_mfma<128, short><<<mgrid, 256, 0, stream>>>(xb, aggb, pWs0, pWn0, b0, h1b);
    hipMemsetAsync(sums, 0, 1024, stream);
    bn_stats_bf16<<<256, 256, 0, stream>>>(h1b, sums, sqs);
    bn_finalize<<<1, 128, 0, stream>>>(sums, sqs, g0, bt0, scl, shf);
    bn_relu_bf16<<<cgrid, 256, 0, stream>>>(h1b, scl, shf);

    // ---- layer 1 ----
    gather_bf16<<<ggrid, 256, 0, stream>>>(h1b, rowptr, esrc, rdeg, aggb);
    sage_mfma<128, short><<<mgrid, 256, 0, stream>>>(h1b, aggb, pWs1, pWn1, b1, h2b);
    hipMemsetAsync(sums, 0, 1024, stream);
    bn_stats_bf16<<<256, 256, 0, stream>>>(h2b, sums, sqs);
    bn_finalize<<<1, 128, 0, stream>>>(sums, sqs, g1, bt1, scl, shf);
    bn_relu_bf16<<<cgrid, 256, 0, stream>>>(h2b, scl, shf);

    // ---- layer 2 ----
    gather_bf16<<<ggrid, 256, 0, stream>>>(h2b, rowptr, esrc, rdeg, aggb);
    sage_mfma<64, float><<<mgrid, 256, 0, stream>>>(h2b, aggb, pWs2, pWn2, b2, out);
}

// Round 4
// 292.852 us; speedup vs baseline: 16.8932x; 1.1149x over previous
//
#include <hip/hip_runtime.h>

#define N_NODES 50000
#define N_EDGES 640000
#define EPS 1e-5f
#define NBLK_SCAN 196   // ceil(50000/256)

typedef __attribute__((ext_vector_type(8))) short short8;
typedef __attribute__((ext_vector_type(4))) float f32x4;

__device__ inline unsigned short f2bf(float f) {
    unsigned u = __float_as_uint(f);
    u += 0x7fffu + ((u >> 16) & 1u);   // RNE
    return (unsigned short)(u >> 16);
}
__device__ inline float bf2f(unsigned short b) {
    return __uint_as_float(((unsigned)b) << 16);
}
__device__ inline void storev(short* p, float v) { *(unsigned short*)p = f2bf(v); }
__device__ inline void storev(float* p, float v) { *p = v; }

// ---------------- CSR build ----------------
__global__ void hist_kernel(const int* __restrict__ dst, int* __restrict__ counts) {
    int e = blockIdx.x * 256 + threadIdx.x;
    if (e < N_EDGES) atomicAdd(&counts[dst[e]], 1);
}

__global__ void scan1_kernel(const int* __restrict__ counts, int* __restrict__ incl,
                             int* __restrict__ bsums) {
    __shared__ int tmp[256];
    int t = threadIdx.x;
    int i = blockIdx.x * 256 + t;
    tmp[t] = (i < N_NODES) ? counts[i] : 0;
    __syncthreads();
    for (int off = 1; off < 256; off <<= 1) {
        int add = (t >= off) ? tmp[t - off] : 0;
        __syncthreads();
        tmp[t] += add;
        __syncthreads();
    }
    if (i < N_NODES) incl[i] = tmp[t];
    if (t == 255) bsums[blockIdx.x] = tmp[255];
}

__global__ void scan2_kernel(const int* __restrict__ bsums, int* __restrict__ boff) {
    __shared__ int tmp[256];
    int t = threadIdx.x;
    tmp[t] = (t < NBLK_SCAN) ? bsums[t] : 0;
    __syncthreads();
    for (int off = 1; off < 256; off <<= 1) {
        int add = (t >= off) ? tmp[t - off] : 0;
        __syncthreads();
        tmp[t] += add;
        __syncthreads();
    }
    if (t < NBLK_SCAN) boff[t] = (t == 0) ? 0 : tmp[t - 1];
}

__global__ void scan3_kernel(const int* __restrict__ counts, const int* __restrict__ incl,
                             const int* __restrict__ boff, int* __restrict__ rowptr,
                             int* __restrict__ cursor, float* __restrict__ rdeg) {
    int i = blockIdx.x * 256 + threadIdx.x;
    if (i >= N_NODES) return;
    int c = counts[i];
    int inc = incl[i] + boff[blockIdx.x];
    int start = inc - c;
    rowptr[i] = start;
    cursor[i] = start;
    rdeg[i] = 1.0f / fmaxf((float)c, 1.0f);
    if (i == N_NODES - 1) rowptr[N_NODES] = inc;
}

__global__ void fill_kernel(const int* __restrict__ src, const int* __restrict__ dst,
                            int* __restrict__ cursor, int* __restrict__ esrc) {
    int e = blockIdx.x * 256 + threadIdx.x;
    if (e < N_EDGES) {
        int p = atomicAdd(&cursor[dst[e]], 1);
        esrc[p] = src[e];
    }
}

// ---------------- x (f32) -> bf16 ----------------
__global__ void xcvt_kernel(const float* __restrict__ in, short* __restrict__ outp) {
    int i = blockIdx.x * 256 + threadIdx.x;       // 8-elem chunk
    if (i >= N_NODES * 16) return;
    const float4* p = (const float4*)in + 2 * (size_t)i;
    float4 a = p[0], b = p[1];
    short8 v;
    v[0] = (short)f2bf(a.x); v[1] = (short)f2bf(a.y);
    v[2] = (short)f2bf(a.z); v[3] = (short)f2bf(a.w);
    v[4] = (short)f2bf(b.x); v[5] = (short)f2bf(b.y);
    v[6] = (short)f2bf(b.z); v[7] = (short)f2bf(b.w);
    *((short8*)outp + i) = v;
}

// ---------------- pack weights (f32 K x NC) into MFMA B-fragment order, bf16 ----
__global__ void pack_w(const float* __restrict__ W, short* __restrict__ Wpk, int NC) {
    int idx = blockIdx.x * 256 + threadIdx.x;
    int total = 4 * (NC / 16) * 64;
    if (idx >= total) return;
    int lane = idx & 63;
    int cbks = idx >> 6;
    int cb = cbks % (NC / 16);
    int ks = cbks / (NC / 16);
    int col = cb * 16 + (lane & 15);
    int k0 = ks * 32 + ((lane >> 4) << 3);
    short8 v;
    #pragma unroll
    for (int j = 0; j < 8; ++j) v[j] = (short)f2bf(W[(size_t)(k0 + j) * NC + col]);
    *((short8*)Wpk + idx) = v;
}

// ---------------- gather mean, 16-deep pipelined, optional fused BN+ReLU ------
// one 64-lane wave per node; lane covers cols 2*lane, 2*lane+1 (4 bytes of bf16)
template<bool BN>
__global__ void gather_k(const short* __restrict__ h, const int* __restrict__ rowptr,
                         const int* __restrict__ esrc, const float* __restrict__ rdeg,
                         const float* __restrict__ scl, const float* __restrict__ shf,
                         short* __restrict__ agg) {
    int node = blockIdx.x * 4 + (threadIdx.x >> 6);
    int lane = threadIdx.x & 63;
    if (node >= N_NODES) return;
    int beg = rowptr[node], end = rowptr[node + 1];
    float s0 = 0.f, s1 = 0.f, b0 = 0.f, b1 = 0.f;
    if (BN) {
        float2 sc = *(const float2*)(scl + lane * 2);
        float2 sh = *(const float2*)(shf + lane * 2);
        s0 = sc.x; s1 = sc.y; b0 = sh.x; b1 = sh.y;
    }
    float ax = 0.f, ay = 0.f;
    while (beg < end) {
        int cnt = min(end - beg, 64);
        int mi = esrc[beg + min(lane, cnt - 1)];
        for (int j = 0; j < cnt; j += 16) {
            int lim = cnt - j; if (lim > 16) lim = 16;
            unsigned v[16];
            #pragma unroll
            for (int u = 0; u < 16; ++u) {
                int s = __shfl(mi, j + (u < lim ? u : lim - 1));
                v[u] = *(const unsigned*)(h + (size_t)s * 128 + lane * 2);
            }
            #pragma unroll
            for (int u = 0; u < 16; ++u) {
                if (u < lim) {
                    float lo = __uint_as_float(v[u] << 16);
                    float hi = __uint_as_float(v[u] & 0xffff0000u);
                    if (BN) {
                        lo = fmaxf(fmaf(lo, s0, b0), 0.f);
                        hi = fmaxf(fmaf(hi, s1, b1), 0.f);
                    }
                    ax += lo; ay += hi;
                }
            }
        }
        beg += cnt;
    }
    float r = rdeg[node];
    unsigned o = ((unsigned)f2bf(ay * r) << 16) | (unsigned)f2bf(ax * r);
    *(unsigned*)(agg + (size_t)node * 128 + lane * 2) = o;
}

// ---------------- MFMA SAGE linear: out = BN?(h)@Ws + agg@Wn + b --------------
// Block = 256 thr = 4 waves; each wave a 16-row strip.
// BNIN: apply scale/shift+relu to h A-frags. STATS: accumulate col sum/sumsq of out.
template<int NC, bool BNIN, bool STATS, typename OUT>
__global__ void sage_mfma(const short* __restrict__ h, const short* __restrict__ agg,
                          const short* __restrict__ Wspk, const short* __restrict__ Wnpk,
                          const float* __restrict__ bias,
                          const float* __restrict__ scl_in, const float* __restrict__ shf_in,
                          float* __restrict__ sums, float* __restrict__ sqs,
                          OUT* __restrict__ out) {
    constexpr int CB = NC / 16;
    __shared__ float ls[128], lq[128];
    const int t = threadIdx.x;
    const int lane = t & 63;
    const int w = t >> 6;
    const int row_base = blockIdx.x * 64 + w * 16;
    const int arow = row_base + (lane & 15);
    const int koff = (lane >> 4) << 3;     // 0,8,16,24

    if (STATS) {
        if (t < NC) { ls[t] = 0.f; lq[t] = 0.f; }
        __syncthreads();
    }

    short8 zero8 = {0, 0, 0, 0, 0, 0, 0, 0};
    short8 ha[4], aa[4];
    if (arow < N_NODES) {
        const short8* hb = (const short8*)(h + (size_t)arow * 128 + koff);
        const short8* ab = (const short8*)(agg + (size_t)arow * 128 + koff);
        #pragma unroll
        for (int ks = 0; ks < 4; ++ks) {
            ha[ks] = hb[ks * 4];
            aa[ks] = ab[ks * 4];
        }
        if (BNIN) {
            #pragma unroll
            for (int ks = 0; ks < 4; ++ks) {
                const float4* scp = (const float4*)(scl_in + ks * 32 + koff);
                const float4* shp = (const float4*)(shf_in + ks * 32 + koff);
                float4 sc0 = scp[0], sc1 = scp[1], sh0 = shp[0], sh1 = shp[1];
                float scv[8] = {sc0.x, sc0.y, sc0.z, sc0.w, sc1.x, sc1.y, sc1.z, sc1.w};
                float shv[8] = {sh0.x, sh0.y, sh0.z, sh0.w, sh1.x, sh1.y, sh1.z, sh1.w};
                short8 v = ha[ks];
                #pragma unroll
                for (int j = 0; j < 8; ++j) {
                    float f = bf2f((unsigned short)v[j]);
                    f = fmaxf(fmaf(f, scv[j], shv[j]), 0.f);
                    v[j] = (short)f2bf(f);
                }
                ha[ks] = v;
            }
        }
    } else {
        #pragma unroll
        for (int ks = 0; ks < 4; ++ks) { ha[ks] = zero8; aa[ks] = zero8; }
    }

    f32x4 zacc = {0.f, 0.f, 0.f, 0.f};
    f32x4 acc[CB];
    #pragma unroll
    for (int c = 0; c < CB; ++c) acc[c] = zacc;

    #pragma unroll
    for (int c = 0; c < CB; ++c) {
        #pragma unroll
        for (int ks = 0; ks < 4; ++ks) {
            short8 b = *((const short8*)Wspk + (ks * CB + c) * 64 + lane);
            acc[c] = __builtin_amdgcn_mfma_f32_16x16x32_bf16(ha[ks], b, acc[c], 0, 0, 0);
        }
        #pragma unroll
        for (int ks = 0; ks < 4; ++ks) {
            short8 b = *((const short8*)Wnpk + (ks * CB + c) * 64 + lane);
            acc[c] = __builtin_amdgcn_mfma_f32_16x16x32_bf16(aa[ks], b, acc[c], 0, 0, 0);
        }
    }

    const int col = lane & 15;
    const int rbase = row_base + ((lane >> 4) << 2);
    #pragma unroll
    for (int c = 0; c < CB; ++c) {
        float bb = bias[c * 16 + col];
        float ps = 0.f, pq = 0.f;
        #pragma unroll
        for (int r = 0; r < 4; ++r) {
            int row = rbase + r;
            if (row < N_NODES) {
                float val = acc[c][r] + bb;
                storev(out + (size_t)row * NC + c * 16 + col, val);
                if (STATS) { ps += val; pq += val * val; }
            }
        }
        if (STATS) {
            atomicAdd(&ls[c * 16 + col], ps);
            atomicAdd(&lq[c * 16 + col], pq);
        }
    }
    if (STATS) {
        __syncthreads();
        if (t < NC) {
            atomicAdd(&sums[t], ls[t]);
            atomicAdd(&sqs[t], lq[t]);
        }
    }
}

__global__ void bn_finalize(const float* __restrict__ sums, const float* __restrict__ sqs,
                            const float* __restrict__ g, const float* __restrict__ beta,
                            float* __restrict__ scale, float* __restrict__ shift) {
    int c = threadIdx.x;
    float mean = sums[c] * (1.0f / N_NODES);
    float var = sqs[c] * (1.0f / N_NODES) - mean * mean;
    float rstd = rsqrtf(var + EPS);
    float sc = rstd * g[c];
    scale[c] = sc;
    shift[c] = beta[c] - mean * sc;
}

extern "C" void kernel_launch(void* const* d_in, const int* in_sizes, int n_in,
                              void* d_out, int out_size, void* d_ws, size_t ws_size,
                              hipStream_t stream) {
    const float* x   = (const float*)d_in[0];
    const int*   src = (const int*)d_in[1];
    const int*   dst = (const int*)d_in[2];
    const float* Ws0 = (const float*)d_in[3];
    const float* Wn0 = (const float*)d_in[4];
    const float* b0  = (const float*)d_in[5];
    const float* Ws1 = (const float*)d_in[6];
    const float* Wn1 = (const float*)d_in[7];
    const float* b1  = (const float*)d_in[8];
    const float* Ws2 = (const float*)d_in[9];
    const float* Wn2 = (const float*)d_in[10];
    const float* b2  = (const float*)d_in[11];
    const float* g0  = (const float*)d_in[12];
    const float* bt0 = (const float*)d_in[13];
    const float* g1  = (const float*)d_in[14];
    const float* bt1 = (const float*)d_in[15];

    char* ws = (char*)d_ws;
    const size_t HB2 = (size_t)N_NODES * 128 * 2;   // bf16 tensor: 12.8 MB
    size_t off = 0;
    short* xb     = (short*)(ws + off); off += HB2;
    short* aggb   = (short*)(ws + off); off += HB2;
    short* h1b    = (short*)(ws + off); off += HB2;
    short* h2b    = (short*)(ws + off); off += HB2;
    int*   esrc   = (int*)(ws + off);   off += (size_t)N_EDGES * 4;
    int*   counts = (int*)(ws + off);   off += 200192;
    int*   incl   = (int*)(ws + off);   off += 200192;
    int*   rowptr = (int*)(ws + off);   off += 200704;
    int*   cursor = (int*)(ws + off);   off += 200192;
    float* rdeg   = (float*)(ws + off); off += 200192;
    int*   bsums  = (int*)(ws + off);   off += 1024;
    int*   boff   = (int*)(ws + off);   off += 1024;
    float* sums0  = (float*)(ws + off); off += 512;
    float* sqs0   = (float*)(ws + off); off += 512;
    float* sums1  = (float*)(ws + off); off += 512;
    float* sqs1   = (float*)(ws + off); off += 512;
    float* scl0   = (float*)(ws + off); off += 512;
    float* shf0   = (float*)(ws + off); off += 512;
    float* scl1   = (float*)(ws + off); off += 512;
    float* shf1   = (float*)(ws + off); off += 512;
    short* pWs0   = (short*)(ws + off); off += 32768;
    short* pWn0   = (short*)(ws + off); off += 32768;
    short* pWs1   = (short*)(ws + off); off += 32768;
    short* pWn1   = (short*)(ws + off); off += 32768;
    short* pWs2   = (short*)(ws + off); off += 16384;
    short* pWn2   = (short*)(ws + off); off += 16384;

    float* out = (float*)d_out;

    const int egrid = (N_EDGES + 255) / 256;       // 2500
    const int ggrid = (N_NODES + 3) / 4;           // 12500
    const int mgrid = (N_NODES + 63) / 64;         // 782
    const int cgrid = (N_NODES * 16 + 255) / 256;  // 3125

    // ---- prep: x->bf16, weight packing, CSR, zero stats ----
    xcvt_kernel<<<cgrid, 256, 0, stream>>>(x, xb);
    pack_w<<<8, 256, 0, stream>>>(Ws0, pWs0, 128);
    pack_w<<<8, 256, 0, stream>>>(Wn0, pWn0, 128);
    pack_w<<<8, 256, 0, stream>>>(Ws1, pWs1, 128);
    pack_w<<<8, 256, 0, stream>>>(Wn1, pWn1, 128);
    pack_w<<<4, 256, 0, stream>>>(Ws2, pWs2, 64);
    pack_w<<<4, 256, 0, stream>>>(Wn2, pWn2, 64);
    hipMemsetAsync(counts, 0, (size_t)N_NODES * 4, stream);
    hipMemsetAsync(sums0, 0, 2048, stream);        // sums0,sqs0,sums1,sqs1
    hist_kernel<<<egrid, 256, 0, stream>>>(dst, counts);
    scan1_kernel<<<NBLK_SCAN, 256, 0, stream>>>(counts, incl, bsums);
    scan2_kernel<<<1, 256, 0, stream>>>(bsums, boff);
    scan3_kernel<<<NBLK_SCAN, 256, 0, stream>>>(counts, incl, boff, rowptr, cursor, rdeg);
    fill_kernel<<<egrid, 256, 0, stream>>>(src, dst, cursor, esrc);

    // ---- layer 0 ----
    gather_k<false><<<ggrid, 256, 0, stream>>>(xb, rowptr, esrc, rdeg, nullptr, nullptr, aggb);
    sage_mfma<128, false, true, short><<<mgrid, 256, 0, stream>>>(
        xb, aggb, pWs0, pWn0, b0, nullptr, nullptr, sums0, sqs0, h1b);
    bn_finalize<<<1, 128, 0, stream>>>(sums0, sqs0, g0, bt0, scl0, shf0);

    // ---- layer 1 ----
    gather_k<true><<<ggrid, 256, 0, stream>>>(h1b, rowptr, esrc, rdeg, scl0, shf0, aggb);
    sage_mfma<128, true, true, short><<<mgrid, 256, 0, stream>>>(
        h1b, aggb, pWs1, pWn1, b1, scl0, shf0, sums1, sqs1, h2b);
    bn_finalize<<<1, 128, 0, stream>>>(sums1, sqs1, g1, bt1, scl1, shf1);

    // ---- layer 2 ----
    gather_k<true><<<ggrid, 256, 0, stream>>>(h2b, rowptr, esrc, rdeg, scl1, shf1, aggb);
    sage_mfma<64, true, false, float><<<mgrid, 256, 0, stream>>>(
        h2b, aggb, pWs2, pWn2, b2, scl1, shf1, nullptr, nullptr, out);
}

// Round 5
// 271.291 us; speedup vs baseline: 18.2359x; 1.0795x over previous
//
#include <hip/hip_runtime.h>

#define N_NODES 50000
#define N_EDGES 640000
#define EPS 1e-5f
#define NBLK_SCAN 196   // ceil(50000/256)

typedef __attribute__((ext_vector_type(8))) short short8;
typedef __attribute__((ext_vector_type(4))) float f32x4;

__device__ inline unsigned short f2bf(float f) {
    unsigned u = __float_as_uint(f);
    u += 0x7fffu + ((u >> 16) & 1u);   // RNE
    return (unsigned short)(u >> 16);
}
__device__ inline float bf2f(unsigned short b) {
    return __uint_as_float(((unsigned)b) << 16);
}
__device__ inline void storev(short* p, float v) { *(unsigned short*)p = f2bf(v); }
__device__ inline void storev(float* p, float v) { *p = v; }

// ---------------- CSR build ----------------
__global__ void hist_kernel(const int* __restrict__ dst, int* __restrict__ counts) {
    int i = blockIdx.x * 256 + threadIdx.x;       // 4 edges per thread
    if (i >= N_EDGES / 4) return;
    int4 d = ((const int4*)dst)[i];
    atomicAdd(&counts[d.x], 1);
    atomicAdd(&counts[d.y], 1);
    atomicAdd(&counts[d.z], 1);
    atomicAdd(&counts[d.w], 1);
}

__global__ void scan1_kernel(const int* __restrict__ counts, int* __restrict__ incl,
                             int* __restrict__ bsums) {
    __shared__ int tmp[256];
    int t = threadIdx.x;
    int i = blockIdx.x * 256 + t;
    tmp[t] = (i < N_NODES) ? counts[i] : 0;
    __syncthreads();
    for (int off = 1; off < 256; off <<= 1) {
        int add = (t >= off) ? tmp[t - off] : 0;
        __syncthreads();
        tmp[t] += add;
        __syncthreads();
    }
    if (i < N_NODES) incl[i] = tmp[t];
    if (t == 255) bsums[blockIdx.x] = tmp[255];
}

__global__ void scan2_kernel(const int* __restrict__ bsums, int* __restrict__ boff) {
    __shared__ int tmp[256];
    int t = threadIdx.x;
    tmp[t] = (t < NBLK_SCAN) ? bsums[t] : 0;
    __syncthreads();
    for (int off = 1; off < 256; off <<= 1) {
        int add = (t >= off) ? tmp[t - off] : 0;
        __syncthreads();
        tmp[t] += add;
        __syncthreads();
    }
    if (t < NBLK_SCAN) boff[t] = (t == 0) ? 0 : tmp[t - 1];
}

__global__ void scan3_kernel(const int* __restrict__ counts, const int* __restrict__ incl,
                             const int* __restrict__ boff, int* __restrict__ rowptr,
                             int* __restrict__ cursor, float* __restrict__ rdeg) {
    int i = blockIdx.x * 256 + threadIdx.x;
    if (i >= N_NODES) return;
    int c = counts[i];
    int inc = incl[i] + boff[blockIdx.x];
    int start = inc - c;
    rowptr[i] = start;
    cursor[i] = start;
    rdeg[i] = 1.0f / fmaxf((float)c, 1.0f);
    if (i == N_NODES - 1) rowptr[N_NODES] = inc;
}

__global__ void fill_kernel(const int* __restrict__ src, const int* __restrict__ dst,
                            int* __restrict__ cursor, int* __restrict__ esrc) {
    int i = blockIdx.x * 256 + threadIdx.x;       // 4 edges per thread
    if (i >= N_EDGES / 4) return;
    int4 d = ((const int4*)dst)[i];
    int4 s = ((const int4*)src)[i];
    int p0 = atomicAdd(&cursor[d.x], 1);
    int p1 = atomicAdd(&cursor[d.y], 1);
    int p2 = atomicAdd(&cursor[d.z], 1);
    int p3 = atomicAdd(&cursor[d.w], 1);
    esrc[p0] = s.x;
    esrc[p1] = s.y;
    esrc[p2] = s.z;
    esrc[p3] = s.w;
}

// ---------------- x (f32) -> bf16 ----------------
__global__ void xcvt_kernel(const float* __restrict__ in, short* __restrict__ outp) {
    int i = blockIdx.x * 256 + threadIdx.x;       // 8-elem chunk
    if (i >= N_NODES * 16) return;
    const float4* p = (const float4*)in + 2 * (size_t)i;
    float4 a = p[0], b = p[1];
    short8 v;
    v[0] = (short)f2bf(a.x); v[1] = (short)f2bf(a.y);
    v[2] = (short)f2bf(a.z); v[3] = (short)f2bf(a.w);
    v[4] = (short)f2bf(b.x); v[5] = (short)f2bf(b.y);
    v[6] = (short)f2bf(b.z); v[7] = (short)f2bf(b.w);
    *((short8*)outp + i) = v;
}

// ---------------- pack all 6 weight matrices into MFMA B-frag order ----------
// Wpk[((ks*(NC/16)+cb)*64 + lane)*8 + j] = W[ks*32 + (lane>>4)*8 + j][cb*16 + (lane&15)]
__global__ void pack_all(const float* __restrict__ W0, const float* __restrict__ W1,
                         const float* __restrict__ W2, const float* __restrict__ W3,
                         const float* __restrict__ W4, const float* __restrict__ W5,
                         short* __restrict__ P0, short* __restrict__ P1,
                         short* __restrict__ P2, short* __restrict__ P3,
                         short* __restrict__ P4, short* __restrict__ P5) {
    int b = blockIdx.x;
    const float* W; short* P; int NC; int base;
    if      (b < 8)  { W = W0; P = P0; NC = 128; base = 0;  }
    else if (b < 16) { W = W1; P = P1; NC = 128; base = 8;  }
    else if (b < 24) { W = W2; P = P2; NC = 128; base = 16; }
    else if (b < 32) { W = W3; P = P3; NC = 128; base = 24; }
    else if (b < 36) { W = W4; P = P4; NC = 64;  base = 32; }
    else             { W = W5; P = P5; NC = 64;  base = 36; }
    int idx = (b - base) * 256 + threadIdx.x;
    int total = 4 * (NC / 16) * 64;
    if (idx >= total) return;
    int lane = idx & 63;
    int cbks = idx >> 6;
    int cb = cbks % (NC / 16);
    int ks = cbks / (NC / 16);
    int col = cb * 16 + (lane & 15);
    int k0 = ks * 32 + ((lane >> 4) << 3);
    short8 v;
    #pragma unroll
    for (int j = 0; j < 8; ++j) v[j] = (short)f2bf(W[(size_t)(k0 + j) * NC + col]);
    *((short8*)P + idx) = v;
}

// ---------------- gather mean, 16-deep pipelined, optional fused BN+ReLU ------
template<bool BN>
__global__ void gather_k(const short* __restrict__ h, const int* __restrict__ rowptr,
                         const int* __restrict__ esrc, const float* __restrict__ rdeg,
                         const float* __restrict__ scl, const float* __restrict__ shf,
                         short* __restrict__ agg) {
    int node = blockIdx.x * 4 + (threadIdx.x >> 6);
    int lane = threadIdx.x & 63;
    if (node >= N_NODES) return;
    int beg = rowptr[node], end = rowptr[node + 1];
    float s0 = 0.f, s1 = 0.f, b0 = 0.f, b1 = 0.f;
    if (BN) {
        float2 sc = *(const float2*)(scl + lane * 2);
        float2 sh = *(const float2*)(shf + lane * 2);
        s0 = sc.x; s1 = sc.y; b0 = sh.x; b1 = sh.y;
    }
    float ax = 0.f, ay = 0.f;
    while (beg < end) {
        int cnt = min(end - beg, 64);
        int mi = esrc[beg + min(lane, cnt - 1)];
        for (int j = 0; j < cnt; j += 16) {
            int lim = cnt - j; if (lim > 16) lim = 16;
            unsigned v[16];
            #pragma unroll
            for (int u = 0; u < 16; ++u) {
                int s = __shfl(mi, j + (u < lim ? u : lim - 1));
                v[u] = *(const unsigned*)(h + (size_t)s * 128 + lane * 2);
            }
            #pragma unroll
            for (int u = 0; u < 16; ++u) {
                if (u < lim) {
                    float lo = __uint_as_float(v[u] << 16);
                    float hi = __uint_as_float(v[u] & 0xffff0000u);
                    if (BN) {
                        lo = fmaxf(fmaf(lo, s0, b0), 0.f);
                        hi = fmaxf(fmaf(hi, s1, b1), 0.f);
                    }
                    ax += lo; ay += hi;
                }
            }
        }
        beg += cnt;
    }
    float r = rdeg[node];
    unsigned o = ((unsigned)f2bf(ay * r) << 16) | (unsigned)f2bf(ax * r);
    *(unsigned*)(agg + (size_t)node * 128 + lane * 2) = o;
}

// ---------------- MFMA SAGE linear: out = BN?(h)@Ws + agg@Wn + b --------------
// Block = 256 thr = 4 waves; each wave a 16-row strip.
// 8 K-slices (Ws ks0..3, Wn ks0..3); B-frags prefetched 2 slices ahead in a
// 3-deep register ring so ~2*CB loads stay in flight over the MFMAs.
#define LOADSLICE(buf, s)                                                       \
    _Pragma("unroll") for (int c = 0; c < CB; ++c)                              \
        buf[c] = ((s) < 4) ? Bs[((s) * CB + c) * 64 + lane]                     \
                           : Bn[(((s) - 4) * CB + c) * 64 + lane];

template<int NC, bool BNIN, bool STATS, typename OUT>
__global__ void sage_mfma(const short* __restrict__ h, const short* __restrict__ agg,
                          const short* __restrict__ Wspk, const short* __restrict__ Wnpk,
                          const float* __restrict__ bias,
                          const float* __restrict__ scl_in, const float* __restrict__ shf_in,
                          float* __restrict__ sums, float* __restrict__ sqs,
                          OUT* __restrict__ out) {
    constexpr int CB = NC / 16;
    __shared__ float ls[128], lq[128];
    const int t = threadIdx.x;
    const int lane = t & 63;
    const int w = t >> 6;
    const int row_base = blockIdx.x * 64 + w * 16;
    const int arow = row_base + (lane & 15);
    const int koff = (lane >> 4) << 3;     // 0,8,16,24

    if (STATS) {
        if (t < NC) { ls[t] = 0.f; lq[t] = 0.f; }
        __syncthreads();
    }

    const short8* Bs = (const short8*)Wspk;
    const short8* Bn = (const short8*)Wnpk;

    short8 zero8 = {0, 0, 0, 0, 0, 0, 0, 0};
    short8 A[8];                            // A[0..3]=h slices, A[4..7]=agg slices
    if (arow < N_NODES) {
        const short8* hb = (const short8*)(h + (size_t)arow * 128 + koff);
        const short8* ab = (const short8*)(agg + (size_t)arow * 128 + koff);
        #pragma unroll
        for (int ks = 0; ks < 4; ++ks) {
            A[ks] = hb[ks * 4];
            A[4 + ks] = ab[ks * 4];
        }
        if (BNIN) {
            #pragma unroll
            for (int ks = 0; ks < 4; ++ks) {
                const float4* scp = (const float4*)(scl_in + ks * 32 + koff);
                const float4* shp = (const float4*)(shf_in + ks * 32 + koff);
                float4 sc0 = scp[0], sc1 = scp[1], sh0 = shp[0], sh1 = shp[1];
                float scv[8] = {sc0.x, sc0.y, sc0.z, sc0.w, sc1.x, sc1.y, sc1.z, sc1.w};
                float shv[8] = {sh0.x, sh0.y, sh0.z, sh0.w, sh1.x, sh1.y, sh1.z, sh1.w};
                short8 v = A[ks];
                #pragma unroll
                for (int j = 0; j < 8; ++j) {
                    float f = bf2f((unsigned short)v[j]);
                    f = fmaxf(fmaf(f, scv[j], shv[j]), 0.f);
                    v[j] = (short)f2bf(f);
                }
                A[ks] = v;
            }
        }
    } else {
        #pragma unroll
        for (int s = 0; s < 8; ++s) A[s] = zero8;
    }

    f32x4 zacc = {0.f, 0.f, 0.f, 0.f};
    f32x4 acc[CB];
    #pragma unroll
    for (int c = 0; c < CB; ++c) acc[c] = zacc;

    short8 ring[3][CB];
    LOADSLICE(ring[0], 0);
    LOADSLICE(ring[1], 1);
    #pragma unroll
    for (int s = 0; s < 8; ++s) {
        if (s + 2 < 8) { LOADSLICE(ring[(s + 2) % 3], s + 2); }
        short8 af = A[s];
        #pragma unroll
        for (int c = 0; c < CB; ++c)
            acc[c] = __builtin_amdgcn_mfma_f32_16x16x32_bf16(af, ring[s % 3][c], acc[c], 0, 0, 0);
    }

    const int col = lane & 15;
    const int rbase = row_base + ((lane >> 4) << 2);
    #pragma unroll
    for (int c = 0; c < CB; ++c) {
        float bb = bias[c * 16 + col];
        float ps = 0.f, pq = 0.f;
        #pragma unroll
        for (int r = 0; r < 4; ++r) {
            int row = rbase + r;
            if (row < N_NODES) {
                float val = acc[c][r] + bb;
                storev(out + (size_t)row * NC + c * 16 + col, val);
                if (STATS) { ps += val; pq += val * val; }
            }
        }
        if (STATS) {
            ps += __shfl_xor(ps, 16); ps += __shfl_xor(ps, 32);
            pq += __shfl_xor(pq, 16); pq += __shfl_xor(pq, 32);
            if (lane < 16) {
                atomicAdd(&ls[c * 16 + col], ps);
                atomicAdd(&lq[c * 16 + col], pq);
            }
        }
    }
    if (STATS) {
        __syncthreads();
        if (t < NC) {
            atomicAdd(&sums[t], ls[t]);
            atomicAdd(&sqs[t], lq[t]);
        }
    }
}

__global__ void bn_finalize(const float* __restrict__ sums, const float* __restrict__ sqs,
                            const float* __restrict__ g, const float* __restrict__ beta,
                            float* __restrict__ scale, float* __restrict__ shift) {
    int c = threadIdx.x;
    float mean = sums[c] * (1.0f / N_NODES);
    float var = sqs[c] * (1.0f / N_NODES) - mean * mean;
    float rstd = rsqrtf(var + EPS);
    float sc = rstd * g[c];
    scale[c] = sc;
    shift[c] = beta[c] - mean * sc;
}

extern "C" void kernel_launch(void* const* d_in, const int* in_sizes, int n_in,
                              void* d_out, int out_size, void* d_ws, size_t ws_size,
                              hipStream_t stream) {
    const float* x   = (const float*)d_in[0];
    const int*   src = (const int*)d_in[1];
    const int*   dst = (const int*)d_in[2];
    const float* Ws0 = (const float*)d_in[3];
    const float* Wn0 = (const float*)d_in[4];
    const float* b0  = (const float*)d_in[5];
    const float* Ws1 = (const float*)d_in[6];
    const float* Wn1 = (const float*)d_in[7];
    const float* b1  = (const float*)d_in[8];
    const float* Ws2 = (const float*)d_in[9];
    const float* Wn2 = (const float*)d_in[10];
    const float* b2  = (const float*)d_in[11];
    const float* g0  = (const float*)d_in[12];
    const float* bt0 = (const float*)d_in[13];
    const float* g1  = (const float*)d_in[14];
    const float* bt1 = (const float*)d_in[15];

    char* ws = (char*)d_ws;
    const size_t HB2 = (size_t)N_NODES * 128 * 2;   // bf16 tensor: 12.8 MB
    size_t off = 0;
    short* xb     = (short*)(ws + off); off += HB2;
    short* aggb   = (short*)(ws + off); off += HB2;
    short* h1b    = (short*)(ws + off); off += HB2;
    short* h2b    = (short*)(ws + off); off += HB2;
    int*   esrc   = (int*)(ws + off);   off += (size_t)N_EDGES * 4;
    int*   counts = (int*)(ws + off);   off += 200192;
    int*   incl   = (int*)(ws + off);   off += 200192;
    int*   rowptr = (int*)(ws + off);   off += 200704;
    int*   cursor = (int*)(ws + off);   off += 200192;
    float* rdeg   = (float*)(ws + off); off += 200192;
    int*   bsums  = (int*)(ws + off);   off += 1024;
    int*   boff   = (int*)(ws + off);   off += 1024;
    float* sums0  = (float*)(ws + off); off += 512;
    float* sqs0   = (float*)(ws + off); off += 512;
    float* sums1  = (float*)(ws + off); off += 512;
    float* sqs1   = (float*)(ws + off); off += 512;
    float* scl0   = (float*)(ws + off); off += 512;
    float* shf0   = (float*)(ws + off); off += 512;
    float* scl1   = (float*)(ws + off); off += 512;
    float* shf1   = (float*)(ws + off); off += 512;
    short* pWs0   = (short*)(ws + off); off += 32768;
    short* pWn0   = (short*)(ws + off); off += 32768;
    short* pWs1   = (short*)(ws + off); off += 32768;
    short* pWn1   = (short*)(ws + off); off += 32768;
    short* pWs2   = (short*)(ws + off); off += 16384;
    short* pWn2   = (short*)(ws + off); off += 16384;

    float* out = (float*)d_out;

    const int e4grid = (N_EDGES / 4 + 255) / 256;   // 625
    const int ggrid  = (N_NODES + 3) / 4;           // 12500
    const int mgrid  = (N_NODES + 63) / 64;         // 782
    const int cgrid  = (N_NODES * 16 + 255) / 256;  // 3125

    // ---- prep: zero, x->bf16, weight packing, CSR ----
    hipMemsetAsync(counts, 0, (size_t)N_NODES * 4, stream);
    hipMemsetAsync(sums0, 0, 2048, stream);         // sums0,sqs0,sums1,sqs1
    xcvt_kernel<<<cgrid, 256, 0, stream>>>(x, xb);
    pack_all<<<40, 256, 0, stream>>>(Ws0, Wn0, Ws1, Wn1, Ws2, Wn2,
                                     pWs0, pWn0, pWs1, pWn1, pWs2, pWn2);
    hist_kernel<<<e4grid, 256, 0, stream>>>(dst, counts);
    scan1_kernel<<<NBLK_SCAN, 256, 0, stream>>>(counts, incl, bsums);
    scan2_kernel<<<1, 256, 0, stream>>>(bsums, boff);
    scan3_kernel<<<NBLK_SCAN, 256, 0, stream>>>(counts, incl, boff, rowptr, cursor, rdeg);
    fill_kernel<<<e4grid, 256, 0, stream>>>(src, dst, cursor, esrc);

    // ---- layer 0 ----
    gather_k<false><<<ggrid, 256, 0, stream>>>(xb, rowptr, esrc, rdeg, nullptr, nullptr, aggb);
    sage_mfma<128, false, true, short><<<mgrid, 256, 0, stream>>>(
        xb, aggb, pWs0, pWn0, b0, nullptr, nullptr, sums0, sqs0, h1b);
    bn_finalize<<<1, 128, 0, stream>>>(sums0, sqs0, g0, bt0, scl0, shf0);

    // ---- layer 1 ----
    gather_k<true><<<ggrid, 256, 0, stream>>>(h1b, rowptr, esrc, rdeg, scl0, shf0, aggb);
    sage_mfma<128, true, true, short><<<mgrid, 256, 0, stream>>>(
        h1b, aggb, pWs1, pWn1, b1, scl0, shf0, sums1, sqs1, h2b);
    bn_finalize<<<1, 128, 0, stream>>>(sums1, sqs1, g1, bt1, scl1, shf1);

    // ---- layer 2 ----
    gather_k<true><<<ggrid, 256, 0, stream>>>(h2b, rowptr, esrc, rdeg, scl1, shf1, aggb);
    sage_mfma<64, true, false, float><<<mgrid, 256, 0, stream>>>(
        h2b, aggb, pWs2, pWn2, b2, scl1, shf1, nullptr, nullptr, out);
}